// Round 1
// baseline (1622.495 us; speedup 1.0000x reference)
//
#include <hip/hip_runtime.h>
#include <cmath>

constexpr int B_ = 4;
constexpr int S_ = 4096;
constexpr int DM_ = 1024;
constexpr int DK_ = 64;
constexpr int NROW = B_ * S_;                       // 16384
constexpr size_t PROJ_ELEMS = (size_t)NROW * DK_;   // 1048576 floats (4 MB)

// ---------------------------------------------------------------------------
// Kernel 1: projections.  Y[r][c] = sum_k X[r][k] * W[c][k] + bias[c]
// One block computes a 64-row x 64-col tile; BK=32; 4x4 micro-tile per thread.
// gridDim.z selects q/k/v.
// ---------------------------------------------------------------------------
__global__ __launch_bounds__(256) void proj_kernel(
    const float* __restrict__ q, const float* __restrict__ k,
    const float* __restrict__ v,
    const float* __restrict__ Wq, const float* __restrict__ bq,
    const float* __restrict__ Wk, const float* __restrict__ bk,
    const float* __restrict__ Wv, const float* __restrict__ bv,
    float* __restrict__ ws) {
  const int mat = blockIdx.z;
  const float* X;
  const float* W;
  const float* bias;
  float* Y;
  if (mat == 0)      { X = q; W = Wq; bias = bq; Y = ws; }
  else if (mat == 1) { X = k; W = Wk; bias = bk; Y = ws + PROJ_ELEMS; }
  else               { X = v; W = Wv; bias = bv; Y = ws + 2 * PROJ_ELEMS; }

  const int row0 = blockIdx.x * 64;
  __shared__ float Xs[64][33];   // pad 33: staggers banks for 4-row strided reads
  __shared__ float Ws[64][33];
  const int t = threadIdx.x;
  const int tq = t >> 4;   // 0..15 -> rows 4*tq..+3
  const int tc = t & 15;   // 0..15 -> cols 4*tc..+3
  float acc[4][4] = {};

  for (int k0 = 0; k0 < DM_; k0 += 32) {
    __syncthreads();
#pragma unroll
    for (int i = 0; i < 8; i++) {
      int e = t + i * 256;        // 0..2047
      int r = e >> 5, kk = e & 31;
      Xs[r][kk] = X[(size_t)(row0 + r) * DM_ + k0 + kk];
      Ws[r][kk] = W[(size_t)r * DM_ + k0 + kk];
    }
    __syncthreads();
#pragma unroll
    for (int kk = 0; kk < 32; kk++) {
      float a[4], bb[4];
#pragma unroll
      for (int i = 0; i < 4; i++) a[i] = Xs[tq * 4 + i][kk];
#pragma unroll
      for (int j = 0; j < 4; j++) bb[j] = Ws[tc * 4 + j][kk];
#pragma unroll
      for (int i = 0; i < 4; i++)
#pragma unroll
        for (int j = 0; j < 4; j++) acc[i][j] += a[i] * bb[j];
    }
  }
#pragma unroll
  for (int i = 0; i < 4; i++) {
    int r = row0 + tq * 4 + i;
#pragma unroll
    for (int j = 0; j < 4; j++) {
      int c = tc * 4 + j;
      Y[(size_t)r * DK_ + c] = acc[i][j] + bias[c];
    }
  }
}

// ---------------------------------------------------------------------------
// Kernel 2: flash-style attention.  One block = (batch b, 32 q-rows).
// Iterates over 128 key-tiles of 32; online softmax; O in registers.
// Thread (qr = t>>3, u = t&7) owns O[qr][8u..8u+7] and does the row
// reductions over its 8-lane group (lanes of one wave) via shfl_xor.
// ---------------------------------------------------------------------------
__global__ __launch_bounds__(256) void attn_kernel(
    const float* __restrict__ ws_in, const int* __restrict__ mask,
    float* __restrict__ o_out) {
  const float* qh = ws_in;
  const float* kh = ws_in + PROJ_ELEMS;
  const float* vh = ws_in + 2 * PROJ_ELEMS;

  const int b = blockIdx.y;
  const int q0 = blockIdx.x * 32;

  __shared__ float qs[32][65];   // pad 65: bank stagger for row-strided reads
  __shared__ float ks[32][65];
  __shared__ float vs[32][68];   // pad 68: keeps 16B alignment for float4 reads
  __shared__ float P[32][33];
  __shared__ int   ms[32][33];

  const int t = threadIdx.x;
  // stage q tile (valid after the first in-loop barrier)
#pragma unroll
  for (int i = 0; i < 8; i++) {
    int e = t + i * 256;
    int r = e >> 6, d = e & 63;
    qs[r][d] = qh[((size_t)b * S_ + q0 + r) * DK_ + d];
  }

  const int qr = t >> 3;          // 0..31
  const int u  = t & 7;           // 0..7 (lane sub-group within wave)
  const int d0 = u * 8;
  const int tq2 = (t >> 4) * 2;   // score phase: 2x2 micro-tile
  const int tk2 = (t & 15) * 2;

  float m_i = -INFINITY, l_i = 0.0f;
  float O[8] = {};

  for (int kt = 0; kt < S_; kt += 32) {
    __syncthreads();   // prior PV readers done before restaging
#pragma unroll
    for (int i = 0; i < 8; i++) {
      int e = t + i * 256;
      int r = e >> 6, d = e & 63;
      ks[r][d] = kh[((size_t)b * S_ + kt + r) * DK_ + d];
      vs[r][d] = vh[((size_t)b * S_ + kt + r) * DK_ + d];
    }
#pragma unroll
    for (int i = 0; i < 4; i++) {
      int e = t + i * 256;
      int r = e >> 5, c = e & 31;
      ms[r][c] = mask[(size_t)(q0 + r) * S_ + kt + c];
    }
    __syncthreads();

    // scores: 2x2 per thread over 64-dim dot
    float s00 = 0, s01 = 0, s10 = 0, s11 = 0;
#pragma unroll
    for (int d = 0; d < 64; d++) {
      float a0 = qs[tq2][d], a1 = qs[tq2 + 1][d];
      float b0 = ks[tk2][d], b1 = ks[tk2 + 1][d];
      s00 += a0 * b0; s01 += a0 * b1; s10 += a1 * b0; s11 += a1 * b1;
    }
    constexpr float scale = 0.125f;   // 1/sqrt(64)
    P[tq2][tk2]         = ms[tq2][tk2]         ? s00 * scale : -1e9f;
    P[tq2][tk2 + 1]     = ms[tq2][tk2 + 1]     ? s01 * scale : -1e9f;
    P[tq2 + 1][tk2]     = ms[tq2 + 1][tk2]     ? s10 * scale : -1e9f;
    P[tq2 + 1][tk2 + 1] = ms[tq2 + 1][tk2 + 1] ? s11 * scale : -1e9f;
    __syncthreads();

    // online softmax: thread (qr,u) reduces P[qr][4u..4u+3] over 8-lane group
    float p0 = P[qr][4 * u], p1 = P[qr][4 * u + 1];
    float p2 = P[qr][4 * u + 2], p3 = P[qr][4 * u + 3];
    float mx = fmaxf(fmaxf(p0, p1), fmaxf(p2, p3));
    mx = fmaxf(mx, __shfl_xor(mx, 1));
    mx = fmaxf(mx, __shfl_xor(mx, 2));
    mx = fmaxf(mx, __shfl_xor(mx, 4));
    float m_new = fmaxf(m_i, mx);
    float alpha = __expf(m_i - m_new);   // first iter: exp(-inf) = 0
    p0 = __expf(p0 - m_new); p1 = __expf(p1 - m_new);
    p2 = __expf(p2 - m_new); p3 = __expf(p3 - m_new);
    float sum = p0 + p1 + p2 + p3;
    sum += __shfl_xor(sum, 1);
    sum += __shfl_xor(sum, 2);
    sum += __shfl_xor(sum, 4);
    l_i = l_i * alpha + sum;
    m_i = m_new;
    P[qr][4 * u] = p0; P[qr][4 * u + 1] = p1;
    P[qr][4 * u + 2] = p2; P[qr][4 * u + 3] = p3;
#pragma unroll
    for (int j = 0; j < 8; j++) O[j] *= alpha;
    __syncthreads();

    // PV: O[qr][d0+j] += sum_kk P[qr][kk] * vs[kk][d0+j]
#pragma unroll
    for (int kk = 0; kk < 32; kk++) {
      float p = P[qr][kk];
#pragma unroll
      for (int j = 0; j < 8; j++) O[j] += p * vs[kk][d0 + j];
    }
  }

  const float inv = 1.0f / l_i;
  float* dst = o_out + ((size_t)b * S_ + q0 + qr) * DK_ + d0;
  float4 o0 = make_float4(O[0] * inv, O[1] * inv, O[2] * inv, O[3] * inv);
  float4 o1 = make_float4(O[4] * inv, O[5] * inv, O[6] * inv, O[7] * inv);
  *(float4*)dst = o0;
  *(float4*)(dst + 4) = o1;
}

// ---------------------------------------------------------------------------
// Kernel 3: output projection.  y[row][c] = sum_k o[row][k]*Wo[c][k] + bo[c]
// Thread owns one output column c; Wo row lives in 64 VGPRs; the 64-float
// o-row is held one-per-lane and broadcast with __shfl (no LDS inner loop).
// ---------------------------------------------------------------------------
__global__ __launch_bounds__(256) void outproj_kernel(
    const float* __restrict__ o_in, const float* __restrict__ Wo,
    const float* __restrict__ bo, float* __restrict__ out) {
  const int c = blockIdx.x * 256 + threadIdx.x;   // 0..1023
  const int row0 = blockIdx.y * 64;
  const int lane = threadIdx.x & 63;

  float w[64];
#pragma unroll
  for (int k4 = 0; k4 < 64; k4 += 4) {
    const float4 wv = *(const float4*)&Wo[(size_t)c * DK_ + k4];
    w[k4] = wv.x; w[k4 + 1] = wv.y; w[k4 + 2] = wv.z; w[k4 + 3] = wv.w;
  }
  const float bias = bo[c];

  for (int r = 0; r < 64; r++) {
    const int row = row0 + r;
    const float ov = o_in[(size_t)row * DK_ + lane];
    float acc = bias;
#pragma unroll
    for (int kk = 0; kk < 64; kk++) {
      const float s = __shfl(ov, kk, 64);
      acc = fmaf(w[kk], s, acc);
    }
    out[(size_t)row * DM_ + c] = acc;
  }
}

// ---------------------------------------------------------------------------
extern "C" void kernel_launch(void* const* d_in, const int* in_sizes, int n_in,
                              void* d_out, int out_size, void* d_ws,
                              size_t ws_size, hipStream_t stream) {
  (void)in_sizes; (void)n_in; (void)out_size; (void)ws_size;
  const float* q  = (const float*)d_in[0];
  const float* k  = (const float*)d_in[1];
  const float* v  = (const float*)d_in[2];
  const int* mask = (const int*)d_in[3];
  const float* Wq = (const float*)d_in[4];
  const float* bq = (const float*)d_in[5];
  const float* Wk = (const float*)d_in[6];
  const float* bk = (const float*)d_in[7];
  const float* Wv = (const float*)d_in[8];
  const float* bv = (const float*)d_in[9];
  const float* Wo = (const float*)d_in[10];
  const float* bo = (const float*)d_in[11];
  float* out = (float*)d_out;
  float* ws  = (float*)d_ws;            // [qh | kh | vh | o] : 16 MB fp32
  float* o_ws = ws + 3 * PROJ_ELEMS;

  proj_kernel<<<dim3(NROW / 64, 1, 3), 256, 0, stream>>>(
      q, k, v, Wq, bq, Wk, bk, Wv, bv, ws);
  attn_kernel<<<dim3(S_ / 32, B_), 256, 0, stream>>>(ws, mask, o_ws);
  outproj_kernel<<<dim3(4, NROW / 64), 256, 0, stream>>>(o_ws, Wo, bo, out);
}

// Round 2
// 457.908 us; speedup vs baseline: 3.5433x; 3.5433x over previous
//
#include <hip/hip_runtime.h>
#include <cmath>

typedef __attribute__((ext_vector_type(8))) short bf16x8;
typedef __attribute__((ext_vector_type(4))) short bf16x4;
typedef __attribute__((ext_vector_type(4))) float f32x4;

constexpr int B_ = 4;
constexpr int S_ = 4096;
constexpr int DM_ = 1024;
constexpr int DK_ = 64;
constexpr int NROW = B_ * S_;   // 16384

__device__ __forceinline__ short f2bf(float x) {
  union { float f; unsigned u; } c; c.f = x;
  unsigned r = (c.u + 0x7FFF + ((c.u >> 16) & 1)) >> 16;  // RNE
  return (short)r;
}
__device__ __forceinline__ float bf2f(short h) {
  union { float f; unsigned u; } c; c.u = ((unsigned)(unsigned short)h) << 16;
  return c.f;
}

// ---------------------------------------------------------------------------
// Kernel 0: pack mask int32 -> bits.  bits[s][k/32] bit (k%32) = mask!=0.
// One wave packs one mask row (4096 elems) via __ballot.
// ---------------------------------------------------------------------------
__global__ __launch_bounds__(256) void maskpack(
    const int* __restrict__ mask, unsigned long long* __restrict__ bits) {
  const int wid = (blockIdx.x * 256 + threadIdx.x) >> 6;  // = s row, 0..4095
  const int lane = threadIdx.x & 63;
  const size_t base = (size_t)wid * 4096;
  for (int it = 0; it < 64; ++it) {
    int m = mask[base + it * 64 + lane];
    unsigned long long b = __ballot(m != 0);
    if (lane == 0) bits[(size_t)wid * 64 + it] = b;
  }
}

// ---------------------------------------------------------------------------
// Kernel 1: projections via bf16 MFMA with hi/lo split on X.
// Tile 128 rows x 64 cols, BK=32.  Writes qh/kh bf16 [row][64]; V transposed:
// vhT[b][d][s] so attention PV fragments are LDS-contiguous.
// ---------------------------------------------------------------------------
__global__ __launch_bounds__(256) void proj_mfma(
    const float* __restrict__ q, const float* __restrict__ k,
    const float* __restrict__ v,
    const float* __restrict__ Wq, const float* __restrict__ bq,
    const float* __restrict__ Wk, const float* __restrict__ bk,
    const float* __restrict__ Wv, const float* __restrict__ bv,
    short* __restrict__ qh, short* __restrict__ kh, short* __restrict__ vhT) {
  const int mat = blockIdx.z;
  const float* X    = mat == 0 ? q  : (mat == 1 ? k  : v);
  const float* W    = mat == 0 ? Wq : (mat == 1 ? Wk : Wv);
  const float* bias = mat == 0 ? bq : (mat == 1 ? bk : bv);

  __shared__ float Xs[128][36];   // stride 36 f32 = 144 B -> 2-way only
  __shared__ short Ws[64][40];    // stride 40 bf16 = 80 B

  const int t = threadIdx.x;
  const int row0 = blockIdx.x * 128;
  const int lane = t & 63, w = t >> 6, quad = lane >> 4, l16 = lane & 15;

  f32x4 acc[2][4] = {};

  for (int k0 = 0; k0 < DM_; k0 += 32) {
    __syncthreads();
    {  // stage X: 128x32 fp32
      int r = t >> 1, off = (t & 1) * 16;
      const float* src = X + (size_t)(row0 + r) * DM_ + k0 + off;
#pragma unroll
      for (int i = 0; i < 4; ++i)
        *(f32x4*)&Xs[r][off + 4 * i] = *(const f32x4*)(src + 4 * i);
    }
    {  // stage W: 64x32 -> bf16
      int c = t >> 2, kk = (t & 3) * 8;
      const float* src = W + (size_t)c * DM_ + k0 + kk;
      f32x4 b0 = *(const f32x4*)src;
      f32x4 b1 = *(const f32x4*)(src + 4);
      bf16x8 wb;
#pragma unroll
      for (int j = 0; j < 4; ++j) { wb[j] = f2bf(b0[j]); wb[j + 4] = f2bf(b1[j]); }
      *(bf16x8*)&Ws[c][kk] = wb;
    }
    __syncthreads();

    bf16x8 bw[4];
#pragma unroll
    for (int ct = 0; ct < 4; ++ct)
      bw[ct] = *(const bf16x8*)&Ws[16 * ct + l16][quad * 8];

#pragma unroll
    for (int rt = 0; rt < 2; ++rt) {
      const float* xp = &Xs[32 * w + 16 * rt + l16][quad * 8];
      f32x4 x0 = *(const f32x4*)xp;
      f32x4 x1 = *(const f32x4*)(xp + 4);
      bf16x8 ahi, alo;
#pragma unroll
      for (int j = 0; j < 4; ++j) {
        short h0 = f2bf(x0[j]); ahi[j] = h0;     alo[j]     = f2bf(x0[j] - bf2f(h0));
        short h1 = f2bf(x1[j]); ahi[j + 4] = h1; alo[j + 4] = f2bf(x1[j] - bf2f(h1));
      }
#pragma unroll
      for (int ct = 0; ct < 4; ++ct) {
        acc[rt][ct] = __builtin_amdgcn_mfma_f32_16x16x32_bf16(ahi, bw[ct], acc[rt][ct], 0, 0, 0);
        acc[rt][ct] = __builtin_amdgcn_mfma_f32_16x16x32_bf16(alo, bw[ct], acc[rt][ct], 0, 0, 0);
      }
    }
  }

  float bs[4];
#pragma unroll
  for (int ct = 0; ct < 4; ++ct) bs[ct] = bias[16 * ct + l16];

  short* dstq = (mat == 0) ? qh : kh;
#pragma unroll
  for (int rt = 0; rt < 2; ++rt)
#pragma unroll
    for (int ct = 0; ct < 4; ++ct)
#pragma unroll
      for (int reg = 0; reg < 4; ++reg) {
        int r = row0 + 32 * w + 16 * rt + quad * 4 + reg;
        int c = 16 * ct + l16;
        short hv = f2bf(acc[rt][ct][reg] + bs[ct]);
        if (mat == 2)
          vhT[((size_t)(r >> 12) * DK_ + c) * S_ + (r & 4095)] = hv;
        else
          dstq[(size_t)r * DK_ + c] = hv;
      }
}

// ---------------------------------------------------------------------------
// Kernel 2: flash attention, bf16 MFMA, transposed formulation.
// Block = (64 q-rows, batch b); wave w owns q-strip 16 rows.  Per 64-key tile:
//   S^T = K·Q^T  (C: col=lane&15=q, row=key)  -> per-lane softmax state
//   P^T -> LDS bf16;  O^T += V^T·P^T.
// ---------------------------------------------------------------------------
__global__ __launch_bounds__(256) void attn_mfma(
    const short* __restrict__ qh, const short* __restrict__ kh,
    const short* __restrict__ vhT, const unsigned int* __restrict__ mbits,
    float* __restrict__ o_ws) {
  __shared__ short ks[64][72];
  __shared__ short vt[64][72];
  __shared__ short ps[4][16][72];

  const int b = blockIdx.y;
  const int q0 = blockIdx.x * 64;
  const int t = threadIdx.x, lane = t & 63, w = t >> 6;
  const int quad = lane >> 4, l16 = lane & 15;
  const int myq = q0 + 16 * w + l16;

  bf16x8 qf[2];
  {
    const short* src = qh + ((size_t)b * S_ + myq) * DK_ + quad * 8;
    qf[0] = *(const bf16x8*)src;
    qf[1] = *(const bf16x8*)(src + 32);
  }

  f32x4 ao[4] = {};
  float m_i = -INFINITY, l_i = 0.0f;

  const int sr = t >> 2;        // staging row 0..63
  const int sseg = t & 3;       // 16B segments sseg, sseg+4

  for (int kt = 0; kt < S_; kt += 64) {
    __syncthreads();
    {
      const short* srck = kh + ((size_t)b * S_ + kt + sr) * DK_;
      *(bf16x8*)&ks[sr][8 * sseg]       = *(const bf16x8*)(srck + 8 * sseg);
      *(bf16x8*)&ks[sr][8 * (sseg + 4)] = *(const bf16x8*)(srck + 8 * (sseg + 4));
      const short* srcv = vhT + ((size_t)b * DK_ + sr) * S_ + kt;
      *(bf16x8*)&vt[sr][8 * sseg]       = *(const bf16x8*)(srcv + 8 * sseg);
      *(bf16x8*)&vt[sr][8 * (sseg + 4)] = *(const bf16x8*)(srcv + 8 * (sseg + 4));
    }
    const uint2 mw = *(const uint2*)&mbits[(size_t)myq * 128 + (kt >> 5)];
    __syncthreads();

    // S^T = K . Q^T
    f32x4 sacc[4] = {};
#pragma unroll
    for (int c = 0; c < 2; ++c)
#pragma unroll
      for (int tt = 0; tt < 4; ++tt) {
        bf16x8 a = *(const bf16x8*)&ks[16 * tt + l16][c * 32 + quad * 8];
        sacc[tt] = __builtin_amdgcn_mfma_f32_16x16x32_bf16(a, qf[c], sacc[tt], 0, 0, 0);
      }

    // mask + scale (bit = key within 32-word)
    float sc[16];
#pragma unroll
    for (int tt = 0; tt < 4; ++tt) {
      unsigned wrd = (tt & 2) ? mw.y : mw.x;
      int base = (tt & 1) * 16 + quad * 4;
#pragma unroll
      for (int r = 0; r < 4; ++r)
        sc[tt * 4 + r] = ((wrd >> (base + r)) & 1) ? sacc[tt][r] * 0.125f : -1e9f;
    }

    // per-lane online softmax (lane owns one q-col; quads hold key-rows)
    float mx = sc[0];
#pragma unroll
    for (int i = 1; i < 16; ++i) mx = fmaxf(mx, sc[i]);
    mx = fmaxf(mx, __shfl_xor(mx, 16));
    mx = fmaxf(mx, __shfl_xor(mx, 32));
    float m_new = fmaxf(m_i, mx);
    float alpha = __expf(m_i - m_new);   // first iter: exp(-inf)=0
    float p[16], sum = 0.0f;
#pragma unroll
    for (int i = 0; i < 16; ++i) { p[i] = __expf(sc[i] - m_new); sum += p[i]; }
    sum += __shfl_xor(sum, 16);
    sum += __shfl_xor(sum, 32);
    l_i = l_i * alpha + sum;
    m_i = m_new;

    // P^T -> LDS (store as ps[q][key]); 4 consecutive keys pack to b64
#pragma unroll
    for (int tt = 0; tt < 4; ++tt) {
      bf16x4 pk;
#pragma unroll
      for (int r = 0; r < 4; ++r) pk[r] = f2bf(p[tt * 4 + r]);
      *(bf16x4*)&ps[w][l16][16 * tt + quad * 4] = pk;
    }

#pragma unroll
    for (int dt = 0; dt < 4; ++dt)
#pragma unroll
      for (int r = 0; r < 4; ++r) ao[dt][r] *= alpha;

    // O^T += V^T . P^T
#pragma unroll
    for (int c = 0; c < 2; ++c) {
      bf16x8 bp = *(const bf16x8*)&ps[w][l16][c * 32 + quad * 8];
#pragma unroll
      for (int dt = 0; dt < 4; ++dt) {
        bf16x8 av = *(const bf16x8*)&vt[16 * dt + l16][c * 32 + quad * 8];
        ao[dt] = __builtin_amdgcn_mfma_f32_16x16x32_bf16(av, bp, ao[dt], 0, 0, 0);
      }
    }
  }

  const float inv = 1.0f / l_i;
#pragma unroll
  for (int dt = 0; dt < 4; ++dt) {
    f32x4 o;
#pragma unroll
    for (int r = 0; r < 4; ++r) o[r] = ao[dt][r] * inv;
    *(f32x4*)&o_ws[((size_t)b * S_ + myq) * DK_ + 16 * dt + quad * 4] = o;
  }
}

// ---------------------------------------------------------------------------
// Kernel 3: output projection, bf16 MFMA.  out[s][dm] = o[s][:].Wo[dm][:] + bo
// Tile 64 s x 256 dm, K=64.
// ---------------------------------------------------------------------------
__global__ __launch_bounds__(256) void outproj_mfma(
    const float* __restrict__ o_in, const float* __restrict__ Wo,
    const float* __restrict__ bo, float* __restrict__ out) {
  __shared__ short os[64][72];
  __shared__ short wos[256][72];

  const int t = threadIdx.x, lane = t & 63, w = t >> 6;
  const int quad = lane >> 4, l16 = lane & 15;
  const int s0 = blockIdx.y * 64;
  const int dm0 = blockIdx.x * 256;

  {  // stage o (fp32 -> bf16)
    int r = t >> 2, cq = (t & 3) * 16;
    const float* src = o_in + (size_t)(s0 + r) * DK_ + cq;
    f32x4 a0 = *(const f32x4*)src, a1 = *(const f32x4*)(src + 4);
    f32x4 a2 = *(const f32x4*)(src + 8), a3 = *(const f32x4*)(src + 12);
    bf16x8 v0, v1;
#pragma unroll
    for (int j = 0; j < 4; ++j) {
      v0[j] = f2bf(a0[j]); v0[j + 4] = f2bf(a1[j]);
      v1[j] = f2bf(a2[j]); v1[j + 4] = f2bf(a3[j]);
    }
    *(bf16x8*)&os[r][cq] = v0;
    *(bf16x8*)&os[r][cq + 8] = v1;
  }
#pragma unroll
  for (int pass = 0; pass < 4; ++pass) {  // stage Wo tile 256x64
    int r = pass * 64 + (t >> 2), cq = (t & 3) * 16;
    const float* src = Wo + (size_t)(dm0 + r) * DK_ + cq;
    f32x4 a0 = *(const f32x4*)src, a1 = *(const f32x4*)(src + 4);
    f32x4 a2 = *(const f32x4*)(src + 8), a3 = *(const f32x4*)(src + 12);
    bf16x8 v0, v1;
#pragma unroll
    for (int j = 0; j < 4; ++j) {
      v0[j] = f2bf(a0[j]); v0[j + 4] = f2bf(a1[j]);
      v1[j] = f2bf(a2[j]); v1[j + 4] = f2bf(a3[j]);
    }
    *(bf16x8*)&wos[r][cq] = v0;
    *(bf16x8*)&wos[r][cq + 8] = v1;
  }
  __syncthreads();

  bf16x8 af[2];
#pragma unroll
  for (int c = 0; c < 2; ++c)
    af[c] = *(const bf16x8*)&os[16 * w + l16][c * 32 + quad * 8];

  f32x4 acc[16] = {};
#pragma unroll
  for (int c = 0; c < 2; ++c)
#pragma unroll
    for (int nt = 0; nt < 16; ++nt) {
      bf16x8 bw = *(const bf16x8*)&wos[16 * nt + l16][c * 32 + quad * 8];
      acc[nt] = __builtin_amdgcn_mfma_f32_16x16x32_bf16(af[c], bw, acc[nt], 0, 0, 0);
    }

  float bias_r[16];
#pragma unroll
  for (int nt = 0; nt < 16; ++nt) bias_r[nt] = bo[dm0 + 16 * nt + l16];

#pragma unroll
  for (int nt = 0; nt < 16; ++nt)
#pragma unroll
    for (int reg = 0; reg < 4; ++reg) {
      int s = s0 + 16 * w + quad * 4 + reg;
      int dm = dm0 + 16 * nt + l16;
      out[(size_t)s * DM_ + dm] = acc[nt][reg] + bias_r[nt];
    }
}

// ---------------------------------------------------------------------------
extern "C" void kernel_launch(void* const* d_in, const int* in_sizes, int n_in,
                              void* d_out, int out_size, void* d_ws,
                              size_t ws_size, hipStream_t stream) {
  (void)in_sizes; (void)n_in; (void)out_size; (void)ws_size;
  const float* q  = (const float*)d_in[0];
  const float* k  = (const float*)d_in[1];
  const float* v  = (const float*)d_in[2];
  const int* mask = (const int*)d_in[3];
  const float* Wq = (const float*)d_in[4];
  const float* bq = (const float*)d_in[5];
  const float* Wk = (const float*)d_in[6];
  const float* bk = (const float*)d_in[7];
  const float* Wv = (const float*)d_in[8];
  const float* bv = (const float*)d_in[9];
  const float* Wo = (const float*)d_in[10];
  const float* bo = (const float*)d_in[11];
  float* out = (float*)d_out;

  // ws layout (bytes): qh 2MB | kh 2MB | vhT 2MB | maskbits 2MB | o 4MB
  short* qh = (short*)d_ws;
  short* kh = qh + (size_t)NROW * DK_;
  short* vhT = kh + (size_t)NROW * DK_;
  unsigned int* mbits = (unsigned int*)(vhT + (size_t)NROW * DK_);
  float* o_ws = (float*)(mbits + (size_t)S_ * 128);

  maskpack<<<1024, 256, 0, stream>>>(mask, (unsigned long long*)mbits);
  proj_mfma<<<dim3(NROW / 128, 1, 3), 256, 0, stream>>>(
      q, k, v, Wq, bq, Wk, bk, Wv, bv, qh, kh, vhT);
  attn_mfma<<<dim3(S_ / 64, B_), 256, 0, stream>>>(qh, kh, vhT, mbits, o_ws);
  outproj_mfma<<<dim3(DM_ / 256, NROW / 64), 256, 0, stream>>>(o_ws, Wo, bo, out);
}

// Round 3
// 387.630 us; speedup vs baseline: 4.1857x; 1.1813x over previous
//
#include <hip/hip_runtime.h>
#include <cmath>

typedef __attribute__((ext_vector_type(8))) short bf16x8;
typedef __attribute__((ext_vector_type(4))) short bf16x4;
typedef __attribute__((ext_vector_type(4))) float f32x4;

constexpr int B_ = 4;
constexpr int S_ = 4096;
constexpr int DM_ = 1024;
constexpr int DK_ = 64;
constexpr int NROW = B_ * S_;   // 16384

__device__ __forceinline__ short f2bf(float x) {
  union { float f; unsigned u; } c; c.f = x;
  unsigned r = (c.u + 0x7FFF + ((c.u >> 16) & 1)) >> 16;  // RNE
  return (short)r;
}
__device__ __forceinline__ float bf2f(short h) {
  union { float f; unsigned u; } c; c.u = ((unsigned)(unsigned short)h) << 16;
  return c.f;
}

// ---------------------------------------------------------------------------
// Kernel 0: pack mask int32 -> bits.  bits[s][k/32] bit (k%32) = mask!=0.
// ---------------------------------------------------------------------------
__global__ __launch_bounds__(256) void maskpack(
    const int* __restrict__ mask, unsigned long long* __restrict__ bits) {
  const int wid = (blockIdx.x * 256 + threadIdx.x) >> 6;  // s row 0..4095
  const int lane = threadIdx.x & 63;
  const size_t base = (size_t)wid * 4096;
  for (int it = 0; it < 64; ++it) {
    int m = mask[base + it * 64 + lane];
    unsigned long long b = __ballot(m != 0);
    if (lane == 0) bits[(size_t)wid * 64 + it] = b;
  }
}

// ---------------------------------------------------------------------------
// Kernel 1: projections, bf16 MFMA, hi/lo split on X.  Tile 128x64, BK=64.
// qh/kh bf16 row-major; V transposed vhT[b][d][s].
// ---------------------------------------------------------------------------
__global__ __launch_bounds__(256) void proj_mfma(
    const float* __restrict__ q, const float* __restrict__ k,
    const float* __restrict__ v,
    const float* __restrict__ Wq, const float* __restrict__ bq,
    const float* __restrict__ Wk, const float* __restrict__ bk,
    const float* __restrict__ Wv, const float* __restrict__ bv,
    short* __restrict__ qh, short* __restrict__ kh, short* __restrict__ vhT) {
  const int mat = blockIdx.z;
  const float* X    = mat == 0 ? q  : (mat == 1 ? k  : v);
  const float* W    = mat == 0 ? Wq : (mat == 1 ? Wk : Wv);
  const float* bias = mat == 0 ? bq : (mat == 1 ? bk : bv);

  __shared__ float Xs[128][68];   // 34.8 KB; stride 68 f32 -> bank step 4
  __shared__ short Ws[64][72];    // 9.2 KB

  const int t = threadIdx.x;
  const int row0 = blockIdx.x * 128;
  const int lane = t & 63, w = t >> 6, quad = lane >> 4, l16 = lane & 15;

  f32x4 acc[2][4] = {};

  for (int k0 = 0; k0 < DM_; k0 += 64) {
    __syncthreads();
    {  // stage X: 128 rows x 64 cols fp32; 8 passes of 32 rows
      const int rr = t >> 3, cc = (t & 7) * 8;
#pragma unroll
      for (int pass = 0; pass < 4; ++pass) {
        int r = pass * 32 + rr;
        const float* src = X + (size_t)(row0 + r) * DM_ + k0 + cc;
        *(f32x4*)&Xs[r][cc]     = *(const f32x4*)src;
        *(f32x4*)&Xs[r][cc + 4] = *(const f32x4*)(src + 4);
      }
    }
    {  // stage W: 64x64 -> bf16
      int c = t >> 2, kk = (t & 3) * 16;
      const float* src = W + (size_t)c * DM_ + k0 + kk;
      f32x4 a0 = *(const f32x4*)src, a1 = *(const f32x4*)(src + 4);
      f32x4 a2 = *(const f32x4*)(src + 8), a3 = *(const f32x4*)(src + 12);
      bf16x8 w0, w1;
#pragma unroll
      for (int j = 0; j < 4; ++j) {
        w0[j] = f2bf(a0[j]); w0[j + 4] = f2bf(a1[j]);
        w1[j] = f2bf(a2[j]); w1[j + 4] = f2bf(a3[j]);
      }
      *(bf16x8*)&Ws[c][kk]     = w0;
      *(bf16x8*)&Ws[c][kk + 8] = w1;
    }
    __syncthreads();

#pragma unroll
    for (int c = 0; c < 2; ++c) {
      bf16x8 bw[4];
#pragma unroll
      for (int ct = 0; ct < 4; ++ct)
        bw[ct] = *(const bf16x8*)&Ws[16 * ct + l16][c * 32 + quad * 8];
#pragma unroll
      for (int rt = 0; rt < 2; ++rt) {
        const float* xp = &Xs[32 * w + 16 * rt + l16][c * 32 + quad * 8];
        f32x4 x0 = *(const f32x4*)xp;
        f32x4 x1 = *(const f32x4*)(xp + 4);
        bf16x8 ahi, alo;
#pragma unroll
        for (int j = 0; j < 4; ++j) {
          short h0 = f2bf(x0[j]); ahi[j] = h0;     alo[j]     = f2bf(x0[j] - bf2f(h0));
          short h1 = f2bf(x1[j]); ahi[j + 4] = h1; alo[j + 4] = f2bf(x1[j] - bf2f(h1));
        }
#pragma unroll
        for (int ct = 0; ct < 4; ++ct) {
          acc[rt][ct] = __builtin_amdgcn_mfma_f32_16x16x32_bf16(ahi, bw[ct], acc[rt][ct], 0, 0, 0);
          acc[rt][ct] = __builtin_amdgcn_mfma_f32_16x16x32_bf16(alo, bw[ct], acc[rt][ct], 0, 0, 0);
        }
      }
    }
  }

  float bs[4];
#pragma unroll
  for (int ct = 0; ct < 4; ++ct) bs[ct] = bias[16 * ct + l16];

  short* dstq = (mat == 0) ? qh : kh;
#pragma unroll
  for (int rt = 0; rt < 2; ++rt)
#pragma unroll
    for (int ct = 0; ct < 4; ++ct)
#pragma unroll
      for (int reg = 0; reg < 4; ++reg) {
        int r = row0 + 32 * w + 16 * rt + quad * 4 + reg;
        int c = 16 * ct + l16;
        short hv = f2bf(acc[rt][ct][reg] + bs[ct]);
        if (mat == 2)
          vhT[((size_t)(r >> 12) * DK_ + c) * S_ + (r & 4095)] = hv;
        else
          dstq[(size_t)r * DK_ + c] = hv;
      }
}

// ---------------------------------------------------------------------------
// Kernel 2: split-K flash attention, bf16 MFMA, transposed formulation.
// blockIdx = (q-tile, split, batch).  Each split covers S_/ns keys, writes
// UNNORMALIZED O^T partials + per-row (m, l).
// ---------------------------------------------------------------------------
__global__ __launch_bounds__(256) void attn_mfma(
    const short* __restrict__ qh, const short* __restrict__ kh,
    const short* __restrict__ vhT, const unsigned int* __restrict__ mbits,
    float* __restrict__ Opart, float* __restrict__ mpart,
    float* __restrict__ lpart, int ns) {
  __shared__ short ks[64][72];
  __shared__ short vt[64][72];
  __shared__ short ps[4][16][72];

  const int b = blockIdx.z;
  const int split = blockIdx.y;
  const int q0 = blockIdx.x * 64;
  const int t = threadIdx.x, lane = t & 63, w = t >> 6;
  const int quad = lane >> 4, l16 = lane & 15;
  const int myq = q0 + 16 * w + l16;

  const int kt0 = split * (S_ / ns);
  const int kt1 = kt0 + S_ / ns;

  bf16x8 qf[2];
  {
    const short* src = qh + ((size_t)b * S_ + myq) * DK_ + quad * 8;
    qf[0] = *(const bf16x8*)src;
    qf[1] = *(const bf16x8*)(src + 32);
  }

  f32x4 ao[4] = {};
  float m_i = -INFINITY, l_i = 0.0f;

  const int sr = t >> 2;        // staging row 0..63
  const int sseg = t & 3;       // 16B segments sseg, sseg+4

  for (int kt = kt0; kt < kt1; kt += 64) {
    __syncthreads();
    {
      const short* srck = kh + ((size_t)b * S_ + kt + sr) * DK_;
      *(bf16x8*)&ks[sr][8 * sseg]       = *(const bf16x8*)(srck + 8 * sseg);
      *(bf16x8*)&ks[sr][8 * (sseg + 4)] = *(const bf16x8*)(srck + 8 * (sseg + 4));
      const short* srcv = vhT + ((size_t)b * DK_ + sr) * S_ + kt;
      *(bf16x8*)&vt[sr][8 * sseg]       = *(const bf16x8*)(srcv + 8 * sseg);
      *(bf16x8*)&vt[sr][8 * (sseg + 4)] = *(const bf16x8*)(srcv + 8 * (sseg + 4));
    }
    const uint2 mw = *(const uint2*)&mbits[(size_t)myq * 128 + (kt >> 5)];
    __syncthreads();

    // S^T = K . Q^T
    f32x4 sacc[4] = {};
#pragma unroll
    for (int c = 0; c < 2; ++c)
#pragma unroll
      for (int tt = 0; tt < 4; ++tt) {
        bf16x8 a = *(const bf16x8*)&ks[16 * tt + l16][c * 32 + quad * 8];
        sacc[tt] = __builtin_amdgcn_mfma_f32_16x16x32_bf16(a, qf[c], sacc[tt], 0, 0, 0);
      }

    // mask + scale
    float sc[16];
#pragma unroll
    for (int tt = 0; tt < 4; ++tt) {
      unsigned wrd = (tt & 2) ? mw.y : mw.x;
      int base = (tt & 1) * 16 + quad * 4;
#pragma unroll
      for (int r = 0; r < 4; ++r)
        sc[tt * 4 + r] = ((wrd >> (base + r)) & 1) ? sacc[tt][r] * 0.125f : -1e9f;
    }

    // per-lane online softmax (lane owns one q-col)
    float mx = sc[0];
#pragma unroll
    for (int i = 1; i < 16; ++i) mx = fmaxf(mx, sc[i]);
    mx = fmaxf(mx, __shfl_xor(mx, 16));
    mx = fmaxf(mx, __shfl_xor(mx, 32));
    float m_new = fmaxf(m_i, mx);
    float alpha = __expf(m_i - m_new);   // first iter: exp(-inf)=0
    float p[16], sum = 0.0f;
#pragma unroll
    for (int i = 0; i < 16; ++i) { p[i] = __expf(sc[i] - m_new); sum += p[i]; }
    sum += __shfl_xor(sum, 16);
    sum += __shfl_xor(sum, 32);
    l_i = l_i * alpha + sum;
    m_i = m_new;

    // P^T -> LDS bf16
#pragma unroll
    for (int tt = 0; tt < 4; ++tt) {
      bf16x4 pk;
#pragma unroll
      for (int r = 0; r < 4; ++r) pk[r] = f2bf(p[tt * 4 + r]);
      *(bf16x4*)&ps[w][l16][16 * tt + quad * 4] = pk;
    }

#pragma unroll
    for (int dt = 0; dt < 4; ++dt)
#pragma unroll
      for (int r = 0; r < 4; ++r) ao[dt][r] *= alpha;

    // O^T += V^T . P^T
#pragma unroll
    for (int c = 0; c < 2; ++c) {
      bf16x8 bp = *(const bf16x8*)&ps[w][l16][c * 32 + quad * 8];
#pragma unroll
      for (int dt = 0; dt < 4; ++dt) {
        bf16x8 av = *(const bf16x8*)&vt[16 * dt + l16][c * 32 + quad * 8];
        ao[dt] = __builtin_amdgcn_mfma_f32_16x16x32_bf16(av, bp, ao[dt], 0, 0, 0);
      }
    }
  }

  const size_t prow = (size_t)split * NROW + (size_t)b * S_ + myq;
#pragma unroll
  for (int dt = 0; dt < 4; ++dt)
    *(f32x4*)&Opart[prow * DK_ + 16 * dt + quad * 4] = ao[dt];
  if (quad == 0) {
    mpart[prow] = m_i;
    lpart[prow] = l_i;
  }
}

// ---------------------------------------------------------------------------
// Kernel 2b: combine split partials -> o bf16.
// ---------------------------------------------------------------------------
__global__ __launch_bounds__(256) void attn_combine(
    const float* __restrict__ Opart, const float* __restrict__ mpart,
    const float* __restrict__ lpart, short* __restrict__ o_bf, int ns) {
  const int t = threadIdx.x;
  const int row = blockIdx.x * 64 + (t >> 2);
  const int c0 = (t & 3) * 16;

  float M = -INFINITY;
  for (int s = 0; s < ns; ++s) M = fmaxf(M, mpart[(size_t)s * NROW + row]);
  float L = 0.0f, wt[4];
  for (int s = 0; s < ns; ++s) {
    wt[s] = __expf(mpart[(size_t)s * NROW + row] - M);
    L += wt[s] * lpart[(size_t)s * NROW + row];
  }
  float acc[16] = {};
  for (int s = 0; s < ns; ++s) {
    const float* src = Opart + ((size_t)s * NROW + row) * DK_ + c0;
#pragma unroll
    for (int j = 0; j < 16; j += 4) {
      f32x4 vv = *(const f32x4*)(src + j);
#pragma unroll
      for (int r = 0; r < 4; ++r) acc[j + r] += wt[s] * vv[r];
    }
  }
  const float inv = 1.0f / L;
  bf16x8 o0, o1;
#pragma unroll
  for (int j = 0; j < 8; ++j) {
    o0[j] = f2bf(acc[j] * inv);
    o1[j] = f2bf(acc[j + 8] * inv);
  }
  *(bf16x8*)&o_bf[(size_t)row * DK_ + c0]     = o0;
  *(bf16x8*)&o_bf[(size_t)row * DK_ + c0 + 8] = o1;
}

// ---------------------------------------------------------------------------
// Kernel 3: output projection, bf16 MFMA.  Tile 64 s x 256 dm, K=64.
// ---------------------------------------------------------------------------
__global__ __launch_bounds__(256) void outproj_mfma(
    const short* __restrict__ o_bf, const float* __restrict__ Wo,
    const float* __restrict__ bo, float* __restrict__ out) {
  __shared__ short os[64][72];
  __shared__ short wos[256][72];

  const int t = threadIdx.x, lane = t & 63, w = t >> 6;
  const int quad = lane >> 4, l16 = lane & 15;
  const int s0 = blockIdx.y * 64;
  const int dm0 = blockIdx.x * 256;

  {  // stage o (bf16 copy)
    int r = t >> 2, cq = (t & 3) * 16;
    const short* src = o_bf + (size_t)(s0 + r) * DK_ + cq;
    *(bf16x8*)&os[r][cq]     = *(const bf16x8*)src;
    *(bf16x8*)&os[r][cq + 8] = *(const bf16x8*)(src + 8);
  }
#pragma unroll
  for (int pass = 0; pass < 4; ++pass) {  // stage Wo tile 256x64 fp32->bf16
    int r = pass * 64 + (t >> 2), cq = (t & 3) * 16;
    const float* src = Wo + (size_t)(dm0 + r) * DK_ + cq;
    f32x4 a0 = *(const f32x4*)src, a1 = *(const f32x4*)(src + 4);
    f32x4 a2 = *(const f32x4*)(src + 8), a3 = *(const f32x4*)(src + 12);
    bf16x8 v0, v1;
#pragma unroll
    for (int j = 0; j < 4; ++j) {
      v0[j] = f2bf(a0[j]); v0[j + 4] = f2bf(a1[j]);
      v1[j] = f2bf(a2[j]); v1[j + 4] = f2bf(a3[j]);
    }
    *(bf16x8*)&wos[r][cq]     = v0;
    *(bf16x8*)&wos[r][cq + 8] = v1;
  }
  __syncthreads();

  bf16x8 af[2];
#pragma unroll
  for (int c = 0; c < 2; ++c)
    af[c] = *(const bf16x8*)&os[16 * w + l16][c * 32 + quad * 8];

  f32x4 acc[16] = {};
#pragma unroll
  for (int c = 0; c < 2; ++c)
#pragma unroll
    for (int nt = 0; nt < 16; ++nt) {
      bf16x8 bw = *(const bf16x8*)&wos[16 * nt + l16][c * 32 + quad * 8];
      acc[nt] = __builtin_amdgcn_mfma_f32_16x16x32_bf16(af[c], bw, acc[nt], 0, 0, 0);
    }

  float bias_r[16];
#pragma unroll
  for (int nt = 0; nt < 16; ++nt) bias_r[nt] = bo[dm0 + 16 * nt + l16];

#pragma unroll
  for (int nt = 0; nt < 16; ++nt)
#pragma unroll
    for (int reg = 0; reg < 4; ++reg) {
      int s = s0 + 16 * w + quad * 4 + reg;
      int dm = dm0 + 16 * nt + l16;
      out[(size_t)s * DM_ + dm] = acc[nt][reg] + bias_r[nt];
    }
}

// ---------------------------------------------------------------------------
extern "C" void kernel_launch(void* const* d_in, const int* in_sizes, int n_in,
                              void* d_out, int out_size, void* d_ws,
                              size_t ws_size, hipStream_t stream) {
  (void)in_sizes; (void)n_in; (void)out_size;
  const float* q  = (const float*)d_in[0];
  const float* k  = (const float*)d_in[1];
  const float* v  = (const float*)d_in[2];
  const int* mask = (const int*)d_in[3];
  const float* Wq = (const float*)d_in[4];
  const float* bq = (const float*)d_in[5];
  const float* Wk = (const float*)d_in[6];
  const float* bk = (const float*)d_in[7];
  const float* Wv = (const float*)d_in[8];
  const float* bv = (const float*)d_in[9];
  const float* Wo = (const float*)d_in[10];
  const float* bo = (const float*)d_in[11];
  float* out = (float*)d_out;

  // ws layout: qh 2MB | kh 2MB | vhT 2MB | mbits 2MB | o_bf 2MB |
  //            mpart 256KB | lpart 256KB | Opart ns*4MB
  short* qh  = (short*)d_ws;
  short* kh  = qh + (size_t)NROW * DK_;
  short* vhT = kh + (size_t)NROW * DK_;
  unsigned int* mbits = (unsigned int*)(vhT + (size_t)NROW * DK_);
  short* o_bf = (short*)(mbits + (size_t)S_ * 128);
  float* mpart = (float*)(o_bf + (size_t)NROW * DK_);
  float* lpart = mpart + 4 * NROW;           // reserved for ns up to 4
  float* Opart = lpart + 4 * NROW;

  const size_t base_bytes = (size_t)((char*)Opart - (char*)d_ws);
  const size_t per_split = (size_t)NROW * DK_ * sizeof(float);   // 4 MB
  int ns = 1;
  if (ws_size >= base_bytes + 4 * per_split) ns = 4;
  else if (ws_size >= base_bytes + 2 * per_split) ns = 2;

  maskpack<<<1024, 256, 0, stream>>>(mask, (unsigned long long*)mbits);
  proj_mfma<<<dim3(NROW / 128, 1, 3), 256, 0, stream>>>(
      q, k, v, Wq, bq, Wk, bk, Wv, bv, qh, kh, vhT);
  attn_mfma<<<dim3(S_ / 64, ns, B_), 256, 0, stream>>>(
      qh, kh, vhT, mbits, Opart, mpart, lpart, ns);
  attn_combine<<<NROW / 64, 256, 0, stream>>>(Opart, mpart, lpart, o_bf, ns);
  outproj_mfma<<<dim3(DM_ / 256, NROW / 64), 256, 0, stream>>>(o_bf, Wo, bo, out);
}